// Round 4
// baseline (39.040 us; speedup 1.0000x reference)
//
#include <hip/hip_runtime.h>
#include <math.h>

// Fuzzyfier: out[b,v,s,p] = mv >= 0.1 ? mv : 0,  mv = exp(-(x-c)^2 / (2 s^2))
// x (64,8,1024) f32, fuzzy_sets (8,64,2) f32 [c, sigma]. Out 134 MB f32.
// HBM-write-bound, floor ~21-30 us.
//
// Numerics: harness ref is numpy in FLOAT64 (R3 evidence: a correctly-rounded
// f32 pipeline still flipped one alpha-cut decision -> the ref's argument
// chain is higher precision than f32). Hybrid: f32 fast path; elements with
// |t - ln 0.1| < 1e-3 (only ones that can flip; ~1e-4 of elements) are
// recomputed fully in f64 (bit-matches numpy's f64 chain; exp_f64 agrees with
// glibc far below the decision scale) and decided against double 0.1.

#define V_DIM 8
#define P_DIM 64
#define LN_CUT -2.3025851f   // ln(0.1), f32
#define BAND 1e-3f

__global__ __launch_bounds__(256) void fuzzyfier_kernel(
    const float* __restrict__ x,     // B*V*S
    const float* __restrict__ fs,    // V*P*2 interleaved (c, sigma)
    float* __restrict__ out,         // B*V*S*P
    int total4)                      // (B*V*S*P)/4
{
    __shared__ float c_s[V_DIM * P_DIM];
    __shared__ float sig_s[V_DIM * P_DIM];
    __shared__ float den_s[V_DIM * P_DIM];   // 2*(s*s), reference op order
    for (int i = threadIdx.x; i < V_DIM * P_DIM; i += 256) {
        float2 cs = reinterpret_cast<const float2*>(fs)[i];
        c_s[i]   = cs.x;
        sig_s[i] = cs.y;
        den_s[i] = 2.0f * (cs.y * cs.y);
    }
    __syncthreads();

    int idx    = blockIdx.x * 256 + threadIdx.x;
    int stride = gridDim.x * 256;

    for (int i = idx; i < total4; i += stride) {
        int q   = (i & 15) << 2;               // p base 0,4,...,60
        int row = i >> 4;                      // b*V*S + v*S + s
        int v   = (row >> 10) & (V_DIM - 1);   // S = 1024
        float xv = x[row];

        int pb = (v << 6) + q;

        float o[4];
        #pragma unroll
        for (int k = 0; k < 4; ++k) {
            float c = c_s[pb + k];
            float d = xv - c;
            float t = -(d * d) / den_s[pb + k];   // IEEE CR f32 chain

            if (__builtin_expect(fabsf(t - LN_CUT) < BAND, 0)) {
                // boundary band: replicate numpy's float64 pipeline exactly
                double dd = (double)xv - (double)c;
                double sd = (double)sig_s[pb + k];
                double td = -(dd * dd) / (2.0 * (sd * sd));
                double md = exp(td);
                o[k] = (md >= 0.1) ? (float)md : 0.0f;
            } else {
                // far from cut: decision is precision-independent
                float m = expf(t);
                o[k] = (m >= 0.1f) ? m : 0.0f;
            }
        }

        float4 ov = make_float4(o[0], o[1], o[2], o[3]);
        reinterpret_cast<float4*>(out)[i] = ov;   // 1 KiB contiguous per wave
    }
}

extern "C" void kernel_launch(void* const* d_in, const int* in_sizes, int n_in,
                              void* d_out, int out_size, void* d_ws, size_t ws_size,
                              hipStream_t stream) {
    const float* x  = (const float*)d_in[0];
    const float* fs = (const float*)d_in[1];
    float* out      = (float*)d_out;

    int total4 = out_size / 4;   // 8,388,608 float4 chunks

    const int block = 256;
    const int grid  = 2048;      // 8 blocks/CU, grid-stride

    hipLaunchKernelGGL(fuzzyfier_kernel, dim3(grid), dim3(block), 0, stream,
                       x, fs, out, total4);
}

// Round 5
// 27.696 us; speedup vs baseline: 1.4096x; 1.4096x over previous
//
#include <hip/hip_runtime.h>
#include <math.h>

// Fuzzyfier: out[b,v,s,p] = mv >= 0.1 ? mv : 0,  mv = exp(-(x-c)^2 / (2 s^2))
// x (64,8,1024) f32, fuzzy_sets (8,64,2) f32 [c, sigma]. Out 134 MB f32.
// Write-bound floor: 134 MB @ 6.7 TB/s (measured fillBuffer ceiling) ~ 20 us.
//
// R4 passed at 39 us = 3.4 TB/s -> VALU-bound (IEEE div + precise expf).
// R5: tolerance is bf16-level (2e-2), so fast path uses fused coefficient
//   w = -log2(e)/(2 s^2);  mv = exp2((d*d)*w)   [6 VALU ops, 1 trans]
// Alpha-cut decisions are protected by the R4-proven f64 band recompute:
// only |u - log2(0.1)| < 2e-3 elements (~1e-4 of all) can flip; fast-path
// decision error scale ~3e-7 << band width.
//
// (v, q) per thread are grid-stride-invariant (stride/16 = 32768 = 4*8192),
// so the 4 (c, w, sigma) triples are hoisted to registers - no LDS, no
// per-iteration index math beyond row = i>>4.

#define LOG2E    1.4426950408889634f
#define LOG2_CUT -3.321928094887362f   // log2(0.1)
#define BAND2    2e-3f

#if __has_builtin(__builtin_amdgcn_exp2f)
#define FAST_EXP2(x) __builtin_amdgcn_exp2f(x)
#else
#define FAST_EXP2(x) exp2f(x)
#endif

__global__ __launch_bounds__(256) void fuzzyfier_kernel(
    const float* __restrict__ x,     // B*V*S
    const float* __restrict__ fs,    // V*P*2 interleaved (c, sigma)
    float* __restrict__ out,         // B*V*S*P
    int total4)                      // (B*V*S*P)/4
{
    int idx    = blockIdx.x * 256 + threadIdx.x;
    int stride = gridDim.x * 256;    // 524288: keeps (v,q) invariant per thread

    int q  = (idx & 15) << 2;              // p base 0,4,...,60 (invariant)
    int v  = ((idx >> 4) >> 10) & 7;       // variable index (invariant)
    int pb = (v << 6) + q;

    float c[4], w[4], sg[4];
    #pragma unroll
    for (int k = 0; k < 4; ++k) {
        float2 cs = reinterpret_cast<const float2*>(fs)[pb + k];  // 4 KB, L2-hot
        c[k]  = cs.x;
        sg[k] = cs.y;
        w[k]  = -LOG2E / (2.0f * (cs.y * cs.y));   // one-time precise div
    }

    for (int i = idx; i < total4; i += stride) {
        int row  = i >> 4;
        float xv = x[row];               // 16 lanes share -> L1 broadcast

        float o[4];
        #pragma unroll
        for (int k = 0; k < 4; ++k) {
            float d = xv - c[k];
            float u = (d * d) * w[k];            // = log2(mv), ~2 ulp
            float m = FAST_EXP2(u);              // v_exp_f32
            o[k] = (m >= 0.1f) ? m : 0.0f;
            if (__builtin_expect(fabsf(u - LOG2_CUT) < BAND2, 0)) {
                // boundary band: replicate numpy's float64 pipeline exactly
                double dd = (double)xv - (double)c[k];
                double sd = (double)sg[k];
                double td = -(dd * dd) / (2.0 * (sd * sd));
                double md = exp(td);
                o[k] = (md >= 0.1) ? (float)md : 0.0f;
            }
        }

        reinterpret_cast<float4*>(out)[i] =
            make_float4(o[0], o[1], o[2], o[3]);   // 1 KiB contiguous per wave
    }
}

extern "C" void kernel_launch(void* const* d_in, const int* in_sizes, int n_in,
                              void* d_out, int out_size, void* d_ws, size_t ws_size,
                              hipStream_t stream) {
    const float* x  = (const float*)d_in[0];
    const float* fs = (const float*)d_in[1];
    float* out      = (float*)d_out;

    int total4 = out_size / 4;   // 8,388,608 float4 chunks

    const int block = 256;
    const int grid  = 2048;      // must stay ==0 mod 512 for (v,q) invariance

    hipLaunchKernelGGL(fuzzyfier_kernel, dim3(grid), dim3(block), 0, stream,
                       x, fs, out, total4);
}